// Round 1
// baseline (227.898 us; speedup 1.0000x reference)
//
#include <hip/hip_runtime.h>

typedef __attribute__((ext_vector_type(8))) _Float16 f16x8;
typedef __attribute__((ext_vector_type(4))) _Float16 f16x4;
typedef __attribute__((ext_vector_type(4))) float    f32x4;
typedef __attribute__((ext_vector_type(4))) int      i32x4;

#define IN_F   4096
#define OUT_F  4096
#define NGRP   32
#define BM     128
#define BN     128
#define BK     64
#define NK     (IN_F / BK)   /* 64 K-steps */

// C[b][o] = sum_k X[b][k] * (q[o][k]-8)*scale[o][k/128]
// 128x128 block tile, 4 waves, each wave a 64x64 subtile = 4x4 frags of
// 16x16x32 f16 MFMA. LDS tiles [row][K] fp16 with XOR swizzle
// byte ^= (row&7)<<4 (T2) applied on BOTH ds_write and ds_read.
__global__ __launch_bounds__(256, 2)
void qgemm_f16(const float* __restrict__ X,
               const int*   __restrict__ QW,
               const float* __restrict__ S,
               float*       __restrict__ C)
{
    __shared__ __align__(16) _Float16 lA[BM * BK];
    __shared__ __align__(16) _Float16 lB[BN * BK];

    const int tid  = threadIdx.x;
    const int lane = tid & 63;

    // XCD-aware bijective swizzle: 1024 blocks, 8 XCDs, 128 blocks/XCD.
    // Consecutive blocks on one XCD sweep N fastest -> share the X panel in L2.
    const int bid = blockIdx.x;
    const int swz = (bid & 7) * 128 + (bid >> 3);
    const int bm0 = (swz >> 5) * BM;   // x-row panel
    const int bn0 = (swz & 31) * BN;   // weight-row panel

    // ---- staging thread mapping ----
    // A: thread -> rows (tid>>4)+16*i, float4 at col (tid&15)*4  (8 loads)
    const int ar = tid >> 4;
    const int ac = tid & 15;
    const float* Ap = X + (size_t)(bm0 + ar) * IN_F + ac * 4;
    // B: thread -> rows (tid>>3)+32*i, int32x4 at packed-col (tid&7)*4 (4 loads)
    const int br = tid >> 3;
    const int bc = tid & 7;
    const int*   Bp = QW + (size_t)(bn0 + br) * (IN_F / 2) + bc * 4;
    const float* Sp = S  + (size_t)(bn0 + br) * NGRP;

    f32x4 av[8];
    i32x4 qv[4];
    float sc[4];

    auto load_tile = [&](int kt) {
        const float* ap = Ap + kt * BK;
#pragma unroll
        for (int i = 0; i < 8; ++i)
            av[i] = *(const f32x4*)(ap + (size_t)i * 16 * IN_F);
        const int* bp = Bp + kt * (BK / 2);
#pragma unroll
        for (int i = 0; i < 4; ++i) {
            qv[i] = *(const i32x4*)(bp + (size_t)i * 32 * (IN_F / 2));
            sc[i] = Sp[(size_t)i * 32 * NGRP + (kt >> 1)];  // group = kt/2 (GS=128=2*BK)
        }
    };

    // ---- wave tile ----
    const int wv  = tid >> 6;
    const int wr  = (wv >> 1) * 64;     // M offset of wave subtile
    const int wc  = (wv & 1)  * 64;     // N offset
    const int lr  = lane & 15;          // fragment row/col within 16
    const int lkb = (lane >> 4) * 16;   // byte offset of lane's 8-elem k-slice

    f32x4 acc[4][4];
#pragma unroll
    for (int m = 0; m < 4; ++m)
#pragma unroll
        for (int n = 0; n < 4; ++n)
            acc[m][n] = (f32x4)0.0f;

    load_tile(0);

    for (int kt = 0; kt < NK; ++kt) {
        __syncthreads();   // previous iteration's ds_reads done -> safe to overwrite
        // A -> LDS (fp32 -> fp16), swizzled 8B writes
#pragma unroll
        for (int i = 0; i < 8; ++i) {
            const int r = ar + i * 16;
            int byt = r * (BK * 2) + ac * 8;
            byt ^= (r & 7) << 4;
            f16x4 h;
            h[0] = (_Float16)av[i][0];
            h[1] = (_Float16)av[i][1];
            h[2] = (_Float16)av[i][2];
            h[3] = (_Float16)av[i][3];
            *(f16x4*)((char*)lA + byt) = h;
        }
        // B -> LDS (int4 dequant -> fp16), swizzled 16B writes
#pragma unroll
        for (int i = 0; i < 4; ++i) {
            const int r = br + i * 32;
            int byt = r * (BK * 2) + bc * 16;
            byt ^= (r & 7) << 4;
            const float s0 = sc[i];
            f16x8 h;
#pragma unroll
            for (int j = 0; j < 4; ++j) {
                const int v = qv[i][j];
                // high nibble = even element, low nibble = odd element
                h[2 * j]     = (_Float16)((float)(((v >> 4) & 15) - 8) * s0);
                h[2 * j + 1] = (_Float16)((float)((v & 15) - 8) * s0);
            }
            *(f16x8*)((char*)lB + byt) = h;
        }
        __syncthreads();

        // issue next tile's global loads now; latency hides under MFMAs (T14-lite)
        if (kt + 1 < NK) load_tile(kt + 1);

#pragma unroll
        for (int kk = 0; kk < 2; ++kk) {
            f16x8 a[4], b[4];
#pragma unroll
            for (int m = 0; m < 4; ++m) {
                const int r = wr + m * 16 + lr;
                int byt = r * (BK * 2) + kk * 64 + lkb;
                byt ^= (r & 7) << 4;
                a[m] = *(const f16x8*)((const char*)lA + byt);
            }
#pragma unroll
            for (int n = 0; n < 4; ++n) {
                const int r = wc + n * 16 + lr;
                int byt = r * (BK * 2) + kk * 64 + lkb;
                byt ^= (r & 7) << 4;
                b[n] = *(const f16x8*)((const char*)lB + byt);
            }
#pragma unroll
            for (int m = 0; m < 4; ++m)
#pragma unroll
                for (int n = 0; n < 4; ++n)
                    acc[m][n] = __builtin_amdgcn_mfma_f32_16x16x32_f16(
                        a[m], b[n], acc[m][n], 0, 0, 0);
        }
    }

    // epilogue: D col = lane&15 (N/o index), row = (lane>>4)*4 + reg (M/b index)
    const int crow = bm0 + wr + (lane >> 4) * 4;
    const int ccol = bn0 + wc + lr;
#pragma unroll
    for (int m = 0; m < 4; ++m)
#pragma unroll
        for (int n = 0; n < 4; ++n)
#pragma unroll
            for (int r = 0; r < 4; ++r)
                C[(size_t)(crow + m * 16 + r) * OUT_F + (ccol + n * 16)]
                    = acc[m][n][r];
}

extern "C" void kernel_launch(void* const* d_in, const int* in_sizes, int n_in,
                              void* d_out, int out_size, void* d_ws, size_t ws_size,
                              hipStream_t stream) {
    (void)in_sizes; (void)n_in; (void)d_ws; (void)ws_size; (void)out_size;
    const float* x  = (const float*)d_in[0];
    const int*   qw = (const int*)d_in[1];
    const float* s  = (const float*)d_in[2];
    float*       out = (float*)d_out;
    qgemm_f16<<<dim3(1024), dim3(256), 0, stream>>>(x, qw, s, out);
}

// Round 2
// 192.564 us; speedup vs baseline: 1.1835x; 1.1835x over previous
//
#include <hip/hip_runtime.h>

typedef __attribute__((ext_vector_type(8))) _Float16 f16x8;
typedef __attribute__((ext_vector_type(4))) float    f32x4;
typedef __attribute__((ext_vector_type(4))) int      i32x4;

#define IN_F   4096
#define OUT_F  4096
#define NGRP   32
#define BM     128
#define BN     128
#define BK     32
#define NK     (IN_F / BK)   /* 128 K-steps */

#define GLOAD_LDS16(gsrc, ldst)                                                   \
    __builtin_amdgcn_global_load_lds(                                             \
        (const __attribute__((address_space(1))) unsigned int*)(gsrc),            \
        (__attribute__((address_space(3))) unsigned int*)(ldst), 16, 0, 0)

// ---------------- prepass 1: X fp32 -> f16 ----------------
__global__ __launch_bounds__(256)
void cvt_x(const float* __restrict__ X, _Float16* __restrict__ Y) {
    size_t i = ((size_t)blockIdx.x * 256 + threadIdx.x) * 8;
    f32x4 a = *(const f32x4*)(X + i);
    f32x4 b = *(const f32x4*)(X + i + 4);
    f16x8 h;
    h[0] = (_Float16)a[0]; h[1] = (_Float16)a[1];
    h[2] = (_Float16)a[2]; h[3] = (_Float16)a[3];
    h[4] = (_Float16)b[0]; h[5] = (_Float16)b[1];
    h[6] = (_Float16)b[2]; h[7] = (_Float16)b[3];
    *(f16x8*)(Y + i) = h;
}

// ---------------- prepass 2: int4 dequant -> f16 ----------------
// qweight int32 (only low byte meaningful): high nibble = even elem, low = odd.
__global__ __launch_bounds__(256)
void deq_w(const int* __restrict__ QW, const float* __restrict__ S,
           _Float16* __restrict__ W) {
    size_t t  = (size_t)blockIdx.x * 256 + threadIdx.x;
    size_t jj = t * 4;                       // int32 index; 2048 per row
    size_t o  = jj >> 11;                    // out-feature row
    size_t jr = jj & 2047;                   // col within row (packed)
    // group = (2*jr)/128 = jr/64; constant across the 4 int32s (4 | 64)
    const float s = S[o * NGRP + (jr >> 6)];
    i32x4 q = *(const i32x4*)(QW + jj);
    f16x8 h;
#pragma unroll
    for (int j = 0; j < 4; ++j) {
        const int v = q[j];
        h[2 * j]     = (_Float16)((float)(((v >> 4) & 15) - 8) * s);
        h[2 * j + 1] = (_Float16)((float)((v & 15) - 8) * s);
    }
    *(f16x8*)(W + jj * 2) = h;
}

// ---------------- main GEMM: m97 structure ----------------
// 128x128 tile, BK=32, 4 waves each 64x64 (4x4 frags of 16x16x32 f16 MFMA),
// global_load_lds width=16 into linear LDS, single buffer, 2 barriers/kt.
__global__ __launch_bounds__(256, 3)
void gemm_f16(const _Float16* __restrict__ A,
              const _Float16* __restrict__ B,
              float*          __restrict__ C)
{
    __shared__ __align__(16) _Float16 lA[BM * BK];   // 8 KB, rows of 64 B
    __shared__ __align__(16) _Float16 lB[BN * BK];   // 8 KB

    const int tid  = threadIdx.x;
    const int lane = tid & 63;

    // XCD-aware bijective swizzle (1024 blocks, 8 XCDs, 128/XCD)
    const int bid = blockIdx.x;
    const int swz = (bid & 7) * 128 + (bid >> 3);
    const int bm0 = (swz >> 5) * BM;
    const int bn0 = (swz & 31) * BN;

    // staging: thread t covers rows t/4 and t/4+64, 8 f16 at col (t&3)*8
    const int sr = tid >> 2;
    const int sc = (tid & 3) * 8;
    const _Float16* Aps = A + (size_t)(bm0 + sr) * IN_F + sc;
    const _Float16* Bps = B + (size_t)(bn0 + sr) * IN_F + sc;
    // wave-uniform LDS bases (dest = base + lane*16 by HW)
    char* lAb = (char*)lA + (tid & ~63) * 16;
    char* lBb = (char*)lB + (tid & ~63) * 16;

    const int wv = tid >> 6;
    const int wr = (wv >> 1) * 64;
    const int wc = (wv & 1)  * 64;
    const int lr  = lane & 15;
    const int lkb = (lane >> 4) * 16;   // byte offset of lane's k-slice

    f32x4 acc[4][4];
#pragma unroll
    for (int m = 0; m < 4; ++m)
#pragma unroll
        for (int n = 0; n < 4; ++n)
            acc[m][n] = (f32x4)0.0f;

    for (int kt = 0; kt < NK; ++kt) {
        __syncthreads();   // prior iteration's ds_reads done
        {
            const _Float16* ak = Aps + kt * BK;
            const _Float16* bk = Bps + kt * BK;
            GLOAD_LDS16(ak, lAb);
            GLOAD_LDS16(ak + (size_t)64 * IN_F, lAb + 4096);
            GLOAD_LDS16(bk, lBb);
            GLOAD_LDS16(bk + (size_t)64 * IN_F, lBb + 4096);
        }
        __syncthreads();   // compiler drains vmcnt(0) before barrier -> tile ready

        f16x8 a[4], b[4];
#pragma unroll
        for (int m = 0; m < 4; ++m)
            a[m] = *(const f16x8*)((const char*)lA + (wr + m * 16 + lr) * (BK * 2) + lkb);
#pragma unroll
        for (int n = 0; n < 4; ++n)
            b[n] = *(const f16x8*)((const char*)lB + (wc + n * 16 + lr) * (BK * 2) + lkb);
#pragma unroll
        for (int m = 0; m < 4; ++m)
#pragma unroll
            for (int n = 0; n < 4; ++n)
                acc[m][n] = __builtin_amdgcn_mfma_f32_16x16x32_f16(
                    a[m], b[n], acc[m][n], 0, 0, 0);
    }

    const int crow = bm0 + wr + (lane >> 4) * 4;
    const int ccol = bn0 + wc + lr;
#pragma unroll
    for (int m = 0; m < 4; ++m)
#pragma unroll
        for (int n = 0; n < 4; ++n)
#pragma unroll
            for (int r = 0; r < 4; ++r)
                C[(size_t)(crow + m * 16 + r) * OUT_F + (ccol + n * 16)]
                    = acc[m][n][r];
}

// ---------------- fallback: round-1 fused kernel (ws too small) ----------------
typedef __attribute__((ext_vector_type(4))) _Float16 f16x4;
__global__ __launch_bounds__(256, 2)
void qgemm_fused(const float* __restrict__ X, const int* __restrict__ QW,
                 const float* __restrict__ S, float* __restrict__ C)
{
    __shared__ __align__(16) _Float16 lA[BM * 64];
    __shared__ __align__(16) _Float16 lB[BN * 64];
    const int tid = threadIdx.x, lane = tid & 63;
    const int bid = blockIdx.x;
    const int swz = (bid & 7) * 128 + (bid >> 3);
    const int bm0 = (swz >> 5) * BM, bn0 = (swz & 31) * BN;
    const int ar = tid >> 4, ac = tid & 15;
    const float* Ap = X + (size_t)(bm0 + ar) * IN_F + ac * 4;
    const int br = tid >> 3, bc = tid & 7;
    const int* Bp = QW + (size_t)(bn0 + br) * (IN_F / 2) + bc * 4;
    const float* Sp = S + (size_t)(bn0 + br) * NGRP;
    f32x4 av[8]; i32x4 qv[4]; float sc4[4];
    auto load_tile = [&](int kt) {
        const float* ap = Ap + kt * 64;
#pragma unroll
        for (int i = 0; i < 8; ++i) av[i] = *(const f32x4*)(ap + (size_t)i * 16 * IN_F);
        const int* bp = Bp + kt * 32;
#pragma unroll
        for (int i = 0; i < 4; ++i) {
            qv[i] = *(const i32x4*)(bp + (size_t)i * 32 * (IN_F / 2));
            sc4[i] = Sp[(size_t)i * 32 * NGRP + (kt >> 1)];
        }
    };
    const int wv = tid >> 6, wr = (wv >> 1) * 64, wc = (wv & 1) * 64;
    const int lr = lane & 15, lkb = (lane >> 4) * 16;
    f32x4 acc[4][4];
#pragma unroll
    for (int m = 0; m < 4; ++m)
#pragma unroll
        for (int n = 0; n < 4; ++n) acc[m][n] = (f32x4)0.0f;
    load_tile(0);
    for (int kt = 0; kt < IN_F / 64; ++kt) {
        __syncthreads();
#pragma unroll
        for (int i = 0; i < 8; ++i) {
            const int r = ar + i * 16; int byt = r * 128 + ac * 8; byt ^= (r & 7) << 4;
            f16x4 h; h[0]=(_Float16)av[i][0]; h[1]=(_Float16)av[i][1];
            h[2]=(_Float16)av[i][2]; h[3]=(_Float16)av[i][3];
            *(f16x4*)((char*)lA + byt) = h;
        }
#pragma unroll
        for (int i = 0; i < 4; ++i) {
            const int r = br + i * 32; int byt = r * 128 + bc * 16; byt ^= (r & 7) << 4;
            const float s0 = sc4[i]; f16x8 h;
#pragma unroll
            for (int j = 0; j < 4; ++j) {
                const int v = qv[i][j];
                h[2*j]   = (_Float16)((float)(((v >> 4) & 15) - 8) * s0);
                h[2*j+1] = (_Float16)((float)((v & 15) - 8) * s0);
            }
            *(f16x8*)((char*)lB + byt) = h;
        }
        __syncthreads();
        if (kt + 1 < IN_F / 64) load_tile(kt + 1);
#pragma unroll
        for (int kk = 0; kk < 2; ++kk) {
            f16x8 a[4], b[4];
#pragma unroll
            for (int m = 0; m < 4; ++m) {
                const int r = wr + m * 16 + lr; int byt = r * 128 + kk * 64 + lkb;
                byt ^= (r & 7) << 4; a[m] = *(const f16x8*)((const char*)lA + byt);
            }
#pragma unroll
            for (int n = 0; n < 4; ++n) {
                const int r = wc + n * 16 + lr; int byt = r * 128 + kk * 64 + lkb;
                byt ^= (r & 7) << 4; b[n] = *(const f16x8*)((const char*)lB + byt);
            }
#pragma unroll
            for (int m = 0; m < 4; ++m)
#pragma unroll
                for (int n = 0; n < 4; ++n)
                    acc[m][n] = __builtin_amdgcn_mfma_f32_16x16x32_f16(a[m], b[n], acc[m][n], 0, 0, 0);
        }
    }
    const int crow = bm0 + wr + (lane >> 4) * 4, ccol = bn0 + wc + lr;
#pragma unroll
    for (int m = 0; m < 4; ++m)
#pragma unroll
        for (int n = 0; n < 4; ++n)
#pragma unroll
            for (int r = 0; r < 4; ++r)
                C[(size_t)(crow + m * 16 + r) * OUT_F + (ccol + n * 16)] = acc[m][n][r];
}

extern "C" void kernel_launch(void* const* d_in, const int* in_sizes, int n_in,
                              void* d_out, int out_size, void* d_ws, size_t ws_size,
                              hipStream_t stream) {
    (void)in_sizes; (void)n_in; (void)out_size;
    const float* x  = (const float*)d_in[0];
    const int*   qw = (const int*)d_in[1];
    const float* s  = (const float*)d_in[2];
    float*       out = (float*)d_out;

    const size_t needed = (size_t)2 * OUT_F * IN_F * sizeof(_Float16); // 64 MB
    if (ws_size >= needed) {
        _Float16* xf = (_Float16*)d_ws;
        _Float16* wf = xf + (size_t)OUT_F * IN_F;
        cvt_x<<<dim3(8192), dim3(256), 0, stream>>>(x, xf);
        deq_w<<<dim3(8192), dim3(256), 0, stream>>>(qw, s, wf);
        gemm_f16<<<dim3(1024), dim3(256), 0, stream>>>(xf, wf, out);
    } else {
        qgemm_fused<<<dim3(1024), dim3(256), 0, stream>>>(x, qw, s, out);
    }
}

// Round 3
// 142.005 us; speedup vs baseline: 1.6049x; 1.3560x over previous
//
#include <hip/hip_runtime.h>

typedef __attribute__((ext_vector_type(8))) _Float16 f16x8;
typedef __attribute__((ext_vector_type(4))) float    f32x4;
typedef __attribute__((ext_vector_type(4))) int      i32x4;

#define IN_F   4096
#define OUT_F  4096
#define NGRP   32
#define NKT    64          /* K-tiles of 64 */

#define GLOAD16(gsrc, ldst)                                                   \
    __builtin_amdgcn_global_load_lds(                                         \
        (const __attribute__((address_space(1))) unsigned int*)(gsrc),        \
        (__attribute__((address_space(3))) unsigned int*)(ldst), 16, 0, 0)

#define CFENCE  asm volatile("" ::: "memory")
#define BARRIER do { CFENCE; __builtin_amdgcn_s_barrier(); CFENCE; } while (0)
#define VMW2    asm volatile("s_waitcnt vmcnt(2)" ::: "memory")

// ---------------- prepass 1: X fp32 -> f16 ----------------
__global__ __launch_bounds__(256)
void cvt_x(const float* __restrict__ X, _Float16* __restrict__ Y) {
    size_t i = ((size_t)blockIdx.x * 256 + threadIdx.x) * 8;
    f32x4 a = *(const f32x4*)(X + i);
    f32x4 b = *(const f32x4*)(X + i + 4);
    f16x8 h;
    h[0] = (_Float16)a[0]; h[1] = (_Float16)a[1];
    h[2] = (_Float16)a[2]; h[3] = (_Float16)a[3];
    h[4] = (_Float16)b[0]; h[5] = (_Float16)b[1];
    h[6] = (_Float16)b[2]; h[7] = (_Float16)b[3];
    *(f16x8*)(Y + i) = h;
}

// ---------------- prepass 2: int4 dequant -> f16 ----------------
__global__ __launch_bounds__(256)
void deq_w(const int* __restrict__ QW, const float* __restrict__ S,
           _Float16* __restrict__ W) {
    size_t t  = (size_t)blockIdx.x * 256 + threadIdx.x;
    size_t jj = t * 4;                       // int32 index; 2048 per row
    size_t o  = jj >> 11;
    size_t jr = jj & 2047;
    const float s = S[o * NGRP + (jr >> 6)];
    i32x4 q = *(const i32x4*)(QW + jj);
    f16x8 h;
#pragma unroll
    for (int j = 0; j < 4; ++j) {
        const int v = q[j];
        h[2 * j]     = (_Float16)((float)(((v >> 4) & 15) - 8) * s);
        h[2 * j + 1] = (_Float16)((float)((v & 15) - 8) * s);
    }
    *(f16x8*)(W + jj * 2) = h;
}

// ---------------- main GEMM: 256^2, BK=64, 8-phase counted-vmcnt ----------------
// LDS (dynamic 128 KB): A halves at ldsA + (buf*2+half)*16384, B at +65536.
// Half-tile = 128 rows x 128 B. T2 swizzle byte ^= ((row&7)<<4) realized as
// pre-swizzled GLOBAL source (linear DMA dest) + swizzled ds_read address.
__global__ __launch_bounds__(512, 2)
void gemm8p(const _Float16* __restrict__ A,
            const _Float16* __restrict__ B,
            float*          __restrict__ C)
{
    extern __shared__ char LDSc[];
    char* const ldsA = LDSc;
    char* const ldsB = LDSc + 65536;

    const int tid  = threadIdx.x;
    const int lane = tid & 63;
    const int wid  = tid >> 6;
    const int wm   = wid >> 2;          // 0..1
    const int wn   = wid & 3;           // 0..3

    const int bid = blockIdx.x;         // 256 blocks (16x16 tiles), %8==0
    const int swz = (bid & 7) * 32 + (bid >> 3);
    const int bm0 = (swz >> 4) * 256;
    const int bn0 = (swz & 15) * 256;

    // staging source: thread covers rows r0 and r0+64 of a half-tile,
    // 16 B at swizzled byte-col cs (involution: src-perm == read-perm)
    const int r0 = tid >> 3;                                // 0..63
    const int cs = ((tid & 7) * 16) ^ ((r0 & 7) << 4);      // 0..127
    const _Float16* Asrc = A + (size_t)(bm0 + r0) * IN_F + (cs >> 1);
    const _Float16* Bsrc = B + (size_t)(bn0 + r0) * IN_F + (cs >> 1);
    const int dstoff = wid * 1024;                          // wave-uniform

    // frag-read offsets (swizzled): row term has row&7 == lane&7
    const int lane15 = lane & 15;
    const int swr = (lane & 7) << 4;
    const int c0 = ((lane >> 4) * 16) ^ swr;        // kk=0 byte col
    const int c1 = (64 + (lane >> 4) * 16) ^ swr;   // kk=1
    int rAoff[4], rBoff[2];
#pragma unroll
    for (int mm = 0; mm < 4; ++mm) rAoff[mm] = (wm * 64 + mm * 16 + lane15) * 128;
#pragma unroll
    for (int nn = 0; nn < 2; ++nn) rBoff[nn] = (wn * 32 + nn * 16 + lane15) * 128;

    f16x8 afr[4][2], blo[2][2], bhi[2][2];
    f32x4 acc[8][4];
#pragma unroll
    for (int m = 0; m < 8; ++m)
#pragma unroll
        for (int n = 0; n < 4; ++n) acc[m][n] = (f32x4)0.0f;

#define STAGE_A(HALF, KT, BUF) do {                                           \
        const _Float16* s_ = Asrc + (size_t)(HALF) * 128 * IN_F + (KT) * 64;  \
        char* d_ = ldsA + ((BUF) * 2 + (HALF)) * 16384 + dstoff;              \
        GLOAD16(s_, d_);                                                      \
        GLOAD16(s_ + (size_t)64 * IN_F, d_ + 8192); } while (0)

#define STAGE_B(HALF, KT, BUF) do {                                           \
        const _Float16* s_ = Bsrc + (size_t)(HALF) * 128 * IN_F + (KT) * 64;  \
        char* d_ = ldsB + ((BUF) * 2 + (HALF)) * 16384 + dstoff;              \
        GLOAD16(s_, d_);                                                      \
        GLOAD16(s_ + (size_t)64 * IN_F, d_ + 8192); } while (0)

#define RD_A(BUF, QM) do { char* ab_ = ldsA + ((BUF) * 2 + (QM)) * 16384;     \
        _Pragma("unroll") for (int mm = 0; mm < 4; ++mm) {                    \
            afr[mm][0] = *(const f16x8*)(ab_ + rAoff[mm] + c0);               \
            afr[mm][1] = *(const f16x8*)(ab_ + rAoff[mm] + c1); } } while (0)

#define RD_B(BUF, QN, DST) do { char* bb_ = ldsB + ((BUF) * 2 + (QN)) * 16384;\
        _Pragma("unroll") for (int nn = 0; nn < 2; ++nn) {                    \
            DST[nn][0] = *(const f16x8*)(bb_ + rBoff[nn] + c0);               \
            DST[nn][1] = *(const f16x8*)(bb_ + rBoff[nn] + c1); } } while (0)

#define MFMA_Q(QM, QN, BQ)                                                    \
        __builtin_amdgcn_s_setprio(1);                                        \
        _Pragma("unroll") for (int mm = 0; mm < 4; ++mm)                      \
        _Pragma("unroll") for (int nn = 0; nn < 2; ++nn)                      \
        _Pragma("unroll") for (int kk = 0; kk < 2; ++kk)                      \
            acc[(QM)*4+mm][(QN)*2+nn] =                                       \
                __builtin_amdgcn_mfma_f32_16x16x32_f16(                       \
                    afr[mm][kk], BQ[nn][kk], acc[(QM)*4+mm][(QN)*2+nn],0,0,0);\
        __builtin_amdgcn_s_setprio(0);

// Issue order (4-phase lead): A-lo, B-lo, B-hi, A-hi. Counted vmcnt(2) at
// P0/P1/P3 fronts retires halves one barrier BEFORE the cross-wave read needs
// them (per-wave vmcnt + trailing barrier publishes all waves' DMA landings).
#define GROUP(BUF, NX) do {                                                   \
        /* P0: quad(0,0) */                                                   \
        VMW2; RD_A(BUF, 0); RD_B(BUF, 0, blo); STAGE_A(0, NX, (BUF) ^ 1);     \
        BARRIER; MFMA_Q(0, 0, blo); BARRIER;                                  \
        /* P1: quad(0,1) */                                                   \
        VMW2; RD_B(BUF, 1, bhi); STAGE_B(0, NX, (BUF) ^ 1);                   \
        BARRIER; MFMA_Q(0, 1, bhi); BARRIER;                                  \
        /* P2: quad(1,0) */                                                   \
        RD_A(BUF, 1); STAGE_B(1, NX, (BUF) ^ 1);                              \
        BARRIER; MFMA_Q(1, 0, blo); BARRIER;                                  \
        /* P3: quad(1,1) */                                                   \
        VMW2; STAGE_A(1, NX, (BUF) ^ 1);                                      \
        BARRIER; MFMA_Q(1, 1, bhi); BARRIER;                                  \
    } while (0)

    // prologue: K-tile 0 -> buf0
    STAGE_A(0, 0, 0); STAGE_B(0, 0, 0); STAGE_B(1, 0, 0); STAGE_A(1, 0, 0);
    asm volatile("s_waitcnt vmcnt(4)" ::: "memory");
    BARRIER;

    for (int t = 0; t < NKT; t += 2) {
        GROUP(0, t + 1);
        GROUP(1, (t + 2) & 63);   // t=62 stages dead K0 -> uniform counts
    }
    asm volatile("s_waitcnt vmcnt(0)" ::: "memory");   // drain DMA before end

#pragma unroll
    for (int m = 0; m < 8; ++m) {
        const int Mr = bm0 + (m >> 2) * 128 + wm * 64 + (m & 3) * 16 + (lane >> 4) * 4;
#pragma unroll
        for (int n = 0; n < 4; ++n) {
            const int Nc = bn0 + (n >> 1) * 128 + wn * 32 + (n & 1) * 16 + lane15;
#pragma unroll
            for (int r = 0; r < 4; ++r)
                C[(size_t)(Mr + r) * OUT_F + Nc] = acc[m][n][r];
        }
    }
#undef STAGE_A
#undef STAGE_B
#undef RD_A
#undef RD_B
#undef MFMA_Q
#undef GROUP
}

// ---------------- fallback: round-2 m97-structure GEMM (static 16 KB LDS) ----
__global__ __launch_bounds__(256, 3)
void gemm_f16(const _Float16* __restrict__ A,
              const _Float16* __restrict__ B,
              float*          __restrict__ C)
{
    __shared__ __align__(16) _Float16 lA[128 * 32];
    __shared__ __align__(16) _Float16 lB[128 * 32];

    const int tid  = threadIdx.x;
    const int lane = tid & 63;
    const int bid = blockIdx.x;
    const int swz = (bid & 7) * 128 + (bid >> 3);
    const int bm0 = (swz >> 5) * 128;
    const int bn0 = (swz & 31) * 128;

    const int sr = tid >> 2;
    const int sc = (tid & 3) * 8;
    const _Float16* Aps = A + (size_t)(bm0 + sr) * IN_F + sc;
    const _Float16* Bps = B + (size_t)(bn0 + sr) * IN_F + sc;
    char* lAb = (char*)lA + (tid & ~63) * 16;
    char* lBb = (char*)lB + (tid & ~63) * 16;

    const int wv = tid >> 6;
    const int wr = (wv >> 1) * 64;
    const int wc = (wv & 1)  * 64;
    const int lr  = lane & 15;
    const int lkb = (lane >> 4) * 16;

    f32x4 acc[4][4];
#pragma unroll
    for (int m = 0; m < 4; ++m)
#pragma unroll
        for (int n = 0; n < 4; ++n) acc[m][n] = (f32x4)0.0f;

    for (int kt = 0; kt < 128; ++kt) {
        __syncthreads();
        {
            const _Float16* ak = Aps + kt * 32;
            const _Float16* bk = Bps + kt * 32;
            GLOAD16(ak, lAb);
            GLOAD16(ak + (size_t)64 * IN_F, lAb + 4096);
            GLOAD16(bk, lBb);
            GLOAD16(bk + (size_t)64 * IN_F, lBb + 4096);
        }
        __syncthreads();

        f16x8 a[4], b[4];
#pragma unroll
        for (int m = 0; m < 4; ++m)
            a[m] = *(const f16x8*)((const char*)lA + (wr + m * 16 + lr) * 64 + lkb);
#pragma unroll
        for (int n = 0; n < 4; ++n)
            b[n] = *(const f16x8*)((const char*)lB + (wc + n * 16 + lr) * 64 + lkb);
#pragma unroll
        for (int m = 0; m < 4; ++m)
#pragma unroll
            for (int n = 0; n < 4; ++n)
                acc[m][n] = __builtin_amdgcn_mfma_f32_16x16x32_f16(
                    a[m], b[n], acc[m][n], 0, 0, 0);
    }

    const int crow = bm0 + wr + (lane >> 4) * 4;
    const int ccol = bn0 + wc + lr;
#pragma unroll
    for (int m = 0; m < 4; ++m)
#pragma unroll
        for (int n = 0; n < 4; ++n)
#pragma unroll
            for (int r = 0; r < 4; ++r)
                C[(size_t)(crow + m * 16 + r) * OUT_F + (ccol + n * 16)]
                    = acc[m][n][r];
}

extern "C" void kernel_launch(void* const* d_in, const int* in_sizes, int n_in,
                              void* d_out, int out_size, void* d_ws, size_t ws_size,
                              hipStream_t stream) {
    (void)in_sizes; (void)n_in; (void)out_size; (void)ws_size;
    const float* x  = (const float*)d_in[0];
    const int*   qw = (const int*)d_in[1];
    const float* s  = (const float*)d_in[2];
    float*       out = (float*)d_out;

    _Float16* xf = (_Float16*)d_ws;
    _Float16* wf = xf + (size_t)OUT_F * IN_F;
    cvt_x<<<dim3(8192), dim3(256), 0, stream>>>(x, xf);
    deq_w<<<dim3(8192), dim3(256), 0, stream>>>(qw, s, wf);

    hipError_t e = hipFuncSetAttribute((const void*)gemm8p,
        hipFuncAttributeMaxDynamicSharedMemorySize, 131072);
    if (e == hipSuccess)
        gemm8p<<<dim3(256), dim3(512), 131072, stream>>>(xf, wf, out);
    else
        gemm_f16<<<dim3(1024), dim3(256), 0, stream>>>(xf, wf, out);
}